// Round 12
// baseline (100.393 us; speedup 1.0000x reference)
//
#include <hip/hip_runtime.h>
#include <hip/hip_bf16.h>

#define HW_   262144   // 512*512
#define C_    256
#define NP_   64
#define BCOLS 128
#define NBLK_ 2048     // HW_/BCOLS
#define SENT  3.0e38f
#define FIXSCALE 1048576.0   // 2^20 fixed-point for deterministic final sum

typedef __attribute__((ext_vector_type(8))) __bf16 bf16x8;
typedef __attribute__((ext_vector_type(4))) float f32x4;

__device__ __forceinline__ void top5_insert(float (&t)[5], float v) {
  if (v < t[4]) {
    t[4] = v;
    if (t[4] < t[3]) { float x = t[3]; t[3] = t[4]; t[4] = x; }
    if (t[3] < t[2]) { float x = t[2]; t[2] = t[3]; t[3] = x; }
    if (t[2] < t[1]) { float x = t[1]; t[1] = t[2]; t[2] = x; }
    if (t[1] < t[0]) { float x = t[0]; t[0] = t[1]; t[1] = x; }
  }
}

// K1: one block per pair; thread t = channel. Emits bf16 sel [pair][chan] + fp32 norms.
// Also zeroes the K3 reduction scratch each call.
__global__ void gather_sel_kernel(const float* __restrict__ f1,
                                  const void* __restrict__ pairs,
                                  unsigned short* __restrict__ selb,  // [64][256] bf16 bits
                                  float* __restrict__ n_p,
                                  unsigned long long* __restrict__ acc,
                                  unsigned* __restrict__ cnt) {
  __shared__ float red[256];
  __shared__ int sidx;
  const int p = blockIdx.x, t = threadIdx.x;
  if (p == 0 && t == 0) { *acc = 0ull; *cnt = 0u; }
  if (t == 0) {
    const long long* ll = (const long long*)pairs;
    const int* ii = (const int*)pairs;
    bool is64 = true;
    for (int k = 0; k < 8; ++k) {
      long long v = ll[k];
      if (v < 0 || v >= (long long)HW_) is64 = false;
    }
    sidx = is64 ? (int)ll[2 * p] : ii[2 * p];
  }
  __syncthreads();
  const int idx = sidx;
  float v = f1[(size_t)t * HW_ + idx];
  __bf16 b = (__bf16)v;
  selb[p * 256 + t] = __builtin_bit_cast(unsigned short, b);
  red[t] = v * v;
  __syncthreads();
  for (int s = 128; s > 0; s >>= 1) {
    if (t < s) red[t] += red[t + s];
    __syncthreads();
  }
  if (t == 0) n_p[p] = red[0];
}

// K2: producer/consumer wave-specialized MFMA GEMM (64 x 262144 x 256).
// 256 thr = 4 waves, 128-col block. Waves 0-1: consumers (64 cols each,
// acc[4][4], pure LDS+MFMA, zero VMEM). Waves 2-3: producers (pure load
// streamers: 16 x float2 contiguous row loads/tile, cvt->bf16, ds_write).
// B tiles: LDS bf16 [32][128] double-buffer (2x8KB), XOR ((row>>3)&3)<<5.
// Sync: raw s_barrier + producer lgkmcnt(0) only -- no vmcnt drain; next
// tile's loads stay in flight across every barrier (compiler counted waits).
// LDS 48KB -> 3 blocks/CU (12 waves/CU, 6 pure streamers).
__global__ __launch_bounds__(256, 3) void dist_topk_kernel(
    const float* __restrict__ f2, const unsigned short* __restrict__ selb,
    const float* __restrict__ n_p, float* __restrict__ cand) {
  __shared__ __align__(16) char smemB[49152];  // [0,32K)=A; [32K,48K)=B dbuf
  float* smemF = (float*)smemB;                // epilogue d-tile [64][128] f32
  const int tid = threadIdx.x;
  const int w = tid >> 6, lane = tid & 63;
  const int m_l = lane & 15, kq = lane >> 4;
  const int j0 = blockIdx.x * BCOLS;
  const int pw = w - 2;   // producer wave index (valid when w>=2)

  // ---- stage A (64x256 bf16 = 32KB) into LDS, byte ^= ((row&7)<<4) swizzle ----
  {
    const uint4* src = (const uint4*)selb;   // 2048 x 16B
#pragma unroll
    for (int i = 0; i < 8; ++i) {
      const int idx = i * 256 + tid;
      const int m = idx >> 5;                // 32 uint4 per 512B row
      unsigned off = (unsigned)(idx * 16) ^ ((m & 7) << 4);
      *(uint4*)(smemB + off) = src[idx];
    }
  }
  __syncthreads();

  f32x4 acc[4][4];
  float njp[4];
  float2 rP[16];
  if (w < 2) {
#pragma unroll
    for (int mt = 0; mt < 4; ++mt)
#pragma unroll
      for (int nt = 0; nt < 4; ++nt) acc[mt][nt] = (f32x4){0.f, 0.f, 0.f, 0.f};
#pragma unroll
    for (int nt = 0; nt < 4; ++nt) njp[nt] = 0.f;
  }

  const float* gbase = f2 + j0 + (lane << 1);   // 2 floats/lane, 512B/row-instr

#define LOADP(T)                                                               \
  _Pragma("unroll") for (int i = 0; i < 16; ++i)                               \
      rP[i] = *(const float2*)(gbase + (size_t)((T) * 32 + pw * 16 + i) * HW_);

#define WRITEP(BUF)                                                            \
  _Pragma("unroll") for (int i = 0; i < 16; ++i) {                             \
    const int r_ = pw * 16 + i;                                                \
    ushort2 pk;                                                                \
    pk.x = __builtin_bit_cast(unsigned short, (__bf16)rP[i].x);                \
    pk.y = __builtin_bit_cast(unsigned short, (__bf16)rP[i].y);                \
    *(ushort2*)(smemB + 32768 + (BUF) * 8192 + r_ * 256 +                      \
                (((unsigned)(lane << 2)) ^ (((r_ >> 3) & 3) << 5))) = pk;      \
  }

#define STEPC(T, BUF)                                                           \
  {                                                                             \
    const char* Bb = smemB + 32768 + (BUF) * 8192;                              \
    bf16x8 afr[4];                                                              \
    _Pragma("unroll") for (int mt = 0; mt < 4; ++mt) {                          \
      unsigned offA =                                                           \
          (unsigned)((mt * 16 + m_l) * 512 + kq * 16 + (T) * 64) ^              \
          ((m_l & 7) << 4);                                                     \
      afr[mt] = *(const bf16x8*)(smemB + offA);                                 \
    }                                                                           \
    bf16x8 bfr[4];                                                              \
    _Pragma("unroll") for (int nt = 0; nt < 4; ++nt) {                          \
      const unsigned cx =                                                       \
          ((unsigned)((w * 64 + nt * 16 + m_l) * 2)) ^ ((unsigned)kq << 5);     \
      _Pragma("unroll") for (int e = 0; e < 8; ++e) {                           \
        unsigned short us =                                                     \
            *(const unsigned short*)(Bb + (kq * 8 + e) * 256 + cx);             \
        bfr[nt][e] = __builtin_bit_cast(__bf16, us);                            \
        float fv = __builtin_bit_cast(float, (unsigned)us << 16);               \
        njp[nt] = fmaf(fv, fv, njp[nt]);                                        \
      }                                                                         \
    }                                                                           \
    _Pragma("unroll") for (int mt = 0; mt < 4; ++mt)                            \
      _Pragma("unroll") for (int nt = 0; nt < 4; ++nt)                          \
        acc[mt][nt] = __builtin_amdgcn_mfma_f32_16x16x32_bf16(                  \
            afr[mt], bfr[nt], acc[mt][nt], 0, 0, 0);                            \
  }

  // ---- prologue: producers stage tile0 into buf0, issue tile1 loads ----
  if (w >= 2) {
    LOADP(0)
    WRITEP(0)          // compiler inserts counted vmcnt for rP reads
    LOADP(1)
    asm volatile("s_waitcnt lgkmcnt(0)" ::: "memory");
  }
  __builtin_amdgcn_s_barrier();
  __builtin_amdgcn_sched_barrier(0);

  // ---- K loop: consumers compute tile T from buf[T&1]; producers write
  //      tile T+1 into buf[(T+1)&1] (loads issued last iter) + issue T+2 ----
#define ITER(T, LAST)                                                          \
  if (w < 2) { STEPC(T, (T) & 1) }                                             \
  else {                                                                       \
    if ((T) < 7) { WRITEP(((T) + 1) & 1) }                                     \
    if ((T) < 6) { LOADP((T) + 2) }                                            \
    asm volatile("s_waitcnt lgkmcnt(0)" ::: "memory");                         \
  }                                                                            \
  if (!(LAST)) {                                                               \
    __builtin_amdgcn_s_barrier();                                              \
    __builtin_amdgcn_sched_barrier(0);                                         \
  }

  ITER(0, 0) ITER(1, 0) ITER(2, 0) ITER(3, 0)
  ITER(4, 0) ITER(5, 0) ITER(6, 0) ITER(7, 1)
#undef ITER
#undef STEPC
#undef WRITEP
#undef LOADP

  // ---- finalize column norms (consumers) ----
  float njc[4];
  if (w < 2) {
#pragma unroll
    for (int nt = 0; nt < 4; ++nt) {
      float v = njp[nt];
      v += __shfl_xor(v, 16);
      v += __shfl_xor(v, 32);
      njc[nt] = v;
    }
  }
  __syncthreads();   // full drain once; A region becomes the d-tile

  // ---- d = relu(n_p + n_j - 2*dot) -> swizzled LDS [64][128] (consumers) ----
  if (w < 2) {
#pragma unroll
    for (int mt = 0; mt < 4; ++mt) {
#pragma unroll
      for (int r = 0; r < 4; ++r) {
        const int pair = mt * 16 + kq * 4 + r;
        const float np = n_p[pair];
#pragma unroll
        for (int nt = 0; nt < 4; ++nt) {
          const int col = w * 64 + nt * 16 + m_l;
          float d = np + njc[nt] - 2.0f * acc[mt][nt][r];
          smemF[pair * 128 + (col ^ (pair & 31))] = fmaxf(d, 0.0f);
        }
      }
    }
  }
  __syncthreads();

  // ---- per-pair top-5 over this block's 128 cols: 4 threads/pair ----
  const int pp = tid & 63, q = tid >> 6;
  float t5[5] = {SENT, SENT, SENT, SENT, SENT};
#pragma unroll 4
  for (int i = 0; i < 32; ++i) {
    const int col = q * 32 + i;
    float v = smemF[pp * 128 + (col ^ (pp & 31))];
    top5_insert(t5, v);
  }
  __syncthreads();
#pragma unroll
  for (int k = 0; k < 5; ++k) smemF[tid * 5 + k] = t5[k];
  __syncthreads();
  if (tid < 64) {
    float m5[5] = {SENT, SENT, SENT, SENT, SENT};
    for (int g = 0; g < 4; ++g)
#pragma unroll
      for (int k = 0; k < 5; ++k) top5_insert(m5, smemF[(g * 64 + tid) * 5 + k]);
    float* cc = cand + (size_t)blockIdx.x * (NP_ * 5) + tid * 5;
#pragma unroll
    for (int k = 0; k < 5; ++k) cc[k] = m5[k];
  }
}

// K3: reduce 2048 blocks' candidates -> per-pair mean of 5 smallest, then
// fused deterministic fixed-point final sum (round-11 proven).
__global__ void topk_reduce_kernel(const float* __restrict__ cand,
                                   unsigned long long* __restrict__ acc,
                                   unsigned* __restrict__ cnt,
                                   float* __restrict__ out) {
  __shared__ float lds[256 * 5];
  const int p = blockIdx.x, tid = threadIdx.x;
  float t5[5] = {SENT, SENT, SENT, SENT, SENT};
  for (int b = tid; b < NBLK_; b += 256) {
    const float* cc = cand + (size_t)b * (NP_ * 5) + p * 5;
#pragma unroll
    for (int k = 0; k < 5; ++k) top5_insert(t5, cc[k]);
  }
#pragma unroll
  for (int k = 0; k < 5; ++k) lds[tid * 5 + k] = t5[k];
  __syncthreads();
  float m2[5] = {SENT, SENT, SENT, SENT, SENT};
  if (tid < 32) {
    for (int t2 = tid * 8; t2 < tid * 8 + 8; ++t2)
#pragma unroll
      for (int k = 0; k < 5; ++k) top5_insert(m2, lds[t2 * 5 + k]);
  }
  __syncthreads();
  if (tid < 32) {
#pragma unroll
    for (int k = 0; k < 5; ++k) lds[tid * 5 + k] = m2[k];
  }
  __syncthreads();
  if (tid == 0) {
    float f[5] = {SENT, SENT, SENT, SENT, SENT};
    for (int t2 = 0; t2 < 32; ++t2)
#pragma unroll
      for (int k = 0; k < 5; ++k) top5_insert(f, lds[t2 * 5 + k]);
    const float mean5 = (f[0] + f[1] + f[2] + f[3] + f[4]) * 0.2f;
    const unsigned long long fx =
        (unsigned long long)(long long)(mean5 * FIXSCALE);  // d >= 0
    atomicAdd(acc, fx);           // device-scope, order-invariant
    __threadfence();
    const unsigned prev = atomicAdd(cnt, 1u);
    if (prev == NP_ - 1) {
      const unsigned long long total = atomicAdd(acc, 0ull);  // coherent read
      out[0] = (float)((double)total / (FIXSCALE * (double)NP_));
    }
  }
}

extern "C" void kernel_launch(void* const* d_in, const int* in_sizes, int n_in,
                              void* d_out, int out_size, void* d_ws, size_t ws_size,
                              hipStream_t stream) {
  const float* f1 = (const float*)d_in[0];
  const float* f2 = (const float*)d_in[1];
  const void* pairs = d_in[2];
  float* out = (float*)d_out;
  float* ws = (float*)d_ws;

  float*              n_p  = ws;                         // 64 f
  unsigned short*     selb = (unsigned short*)(ws + 64); // 16384 ushort (32KB)
  float*              cand = ws + 64 + 8192;             // 2048*64*5 = 655360 f
  unsigned long long* acc  = (unsigned long long*)(ws + 64 + 8192 + 655360);
  unsigned*           cnt  = (unsigned*)(ws + 64 + 8192 + 655360 + 2);

  gather_sel_kernel<<<NP_, 256, 0, stream>>>(f1, pairs, selb, n_p, acc, cnt);
  dist_topk_kernel<<<NBLK_, 256, 0, stream>>>(f2, selb, n_p, cand);
  topk_reduce_kernel<<<NP_, 256, 0, stream>>>(cand, acc, cnt, out);
}

// Round 13
// 82.374 us; speedup vs baseline: 1.2187x; 1.2187x over previous
//
#include <hip/hip_runtime.h>
#include <hip/hip_bf16.h>

#define HW_   262144   // 512*512
#define C_    256
#define NP_   64
#define NBLK_ 1024     // HW_/256 cols per block
#define SENT  3.0e38f
#define FIXSCALE 1048576.0   // 2^20 fixed-point for deterministic final sum

typedef __attribute__((ext_vector_type(8))) __bf16 bf16x8;
typedef __attribute__((ext_vector_type(4))) float f32x4;

__device__ __forceinline__ void top5_insert(float (&t)[5], float v) {
  if (v < t[4]) {
    t[4] = v;
    if (t[4] < t[3]) { float x = t[3]; t[3] = t[4]; t[4] = x; }
    if (t[3] < t[2]) { float x = t[2]; t[2] = t[3]; t[3] = x; }
    if (t[2] < t[1]) { float x = t[1]; t[1] = t[2]; t[2] = x; }
    if (t[1] < t[0]) { float x = t[0]; t[0] = t[1]; t[1] = x; }
  }
}

// K1: one block per pair; thread t = channel. Emits bf16 sel [pair][chan] + fp32 norms.
// Also zeroes the K3 reduction scratch (acc/cnt) each call.
__global__ void gather_sel_kernel(const float* __restrict__ f1,
                                  const void* __restrict__ pairs,
                                  unsigned short* __restrict__ selb,  // [64][256] bf16 bits
                                  float* __restrict__ n_p,
                                  unsigned long long* __restrict__ acc,
                                  unsigned* __restrict__ cnt) {
  __shared__ float red[256];
  __shared__ int sidx;
  const int p = blockIdx.x, t = threadIdx.x;
  if (p == 0 && t == 0) { *acc = 0ull; *cnt = 0u; }
  if (t == 0) {
    const long long* ll = (const long long*)pairs;
    const int* ii = (const int*)pairs;
    bool is64 = true;
    for (int k = 0; k < 8; ++k) {
      long long v = ll[k];
      if (v < 0 || v >= (long long)HW_) is64 = false;
    }
    sidx = is64 ? (int)ll[2 * p] : ii[2 * p];
  }
  __syncthreads();
  const int idx = sidx;
  float v = f1[(size_t)t * HW_ + idx];
  __bf16 b = (__bf16)v;
  selb[p * 256 + t] = __builtin_bit_cast(unsigned short, b);
  red[t] = v * v;
  __syncthreads();
  for (int s = 128; s > 0; s >>= 1) {
    if (t < s) red[t] += red[t + s];
    __syncthreads();
  }
  if (t == 0) n_p[p] = red[0];
}

// K2: best-known variant (round 6/11): register triple-buffer B, zero K-loop
// barriers, 512 thr = 8 waves, wave w owns cols [j0+32w, j0+32w+32).
__global__ __launch_bounds__(512, 4) void dist_topk_kernel(
    const float* __restrict__ f2, const unsigned short* __restrict__ selb,
    const float* __restrict__ n_p, float* __restrict__ cand) {
  __shared__ float smem[64 * 256];   // 64 KB; bytes [0,32K) double as A-tile
  char* smemB = (char*)smem;
  const int tid = threadIdx.x;
  const int w = tid >> 6, lane = tid & 63;
  const int m_l = lane & 15, kq = lane >> 4;
  const int j0 = blockIdx.x * 256;

  // ---- stage A (64x256 bf16 = 32KB) into LDS, byte ^= ((row&7)<<4) swizzle ----
  {
    const uint4* src = (const uint4*)selb;            // 2048 x 16B
#pragma unroll
    for (int i = 0; i < 4; ++i) {
      const int idx = i * 512 + tid;
      const int m = idx >> 5;                          // 32 uint4 per 512B row
      unsigned off = (unsigned)(idx * 16) ^ ((m & 7) << 4);
      *(uint4*)(smemB + off) = src[idx];
    }
  }
  __syncthreads();

  const unsigned colbase = (unsigned)(j0 + w * 32 + m_l);
  const unsigned rowbase = (unsigned)(kq * 8) * HW_;

  f32x4 acc[4][2];
#pragma unroll
  for (int mt = 0; mt < 4; ++mt)
#pragma unroll
    for (int nt = 0; nt < 2; ++nt) acc[mt][nt] = (f32x4){0.f, 0.f, 0.f, 0.f};
  float njp[2] = {0.f, 0.f};

  float b0[16], b1[16], b2[16];
#define LOADB(BUF, T)                                                          \
  _Pragma("unroll") for (int nt = 0; nt < 2; ++nt)                             \
  _Pragma("unroll") for (int e = 0; e < 8; ++e)                                \
      BUF[nt * 8 + e] =                                                        \
          f2[rowbase + colbase + (unsigned)(((T) * 32 + e) * HW_ + nt * 16)];

  LOADB(b0, 0)
  LOADB(b1, 1)

#define STEP(CUR, NXT, T, PF)                                                   \
  {                                                                             \
    if (PF) { LOADB(NXT, (T) + 2) }                                             \
    bf16x8 afr[4];                                                              \
    _Pragma("unroll") for (int mt = 0; mt < 4; ++mt) {                          \
      unsigned offA =                                                           \
          (unsigned)((mt * 16 + m_l) * 512 + kq * 16 + (T) * 64) ^              \
          ((m_l & 7) << 4);                                                     \
      afr[mt] = *(const bf16x8*)(smemB + offA);                                 \
    }                                                                           \
    bf16x8 bfr[2];                                                              \
    _Pragma("unroll") for (int nt = 0; nt < 2; ++nt) {                          \
      _Pragma("unroll") for (int e = 0; e < 8; ++e) {                           \
        float v = CUR[nt * 8 + e];                                              \
        njp[nt] = fmaf(v, v, njp[nt]);                                          \
        bfr[nt][e] = (__bf16)v;                                                 \
      }                                                                         \
    }                                                                           \
    _Pragma("unroll") for (int mt = 0; mt < 4; ++mt)                            \
      _Pragma("unroll") for (int nt = 0; nt < 2; ++nt)                          \
        acc[mt][nt] = __builtin_amdgcn_mfma_f32_16x16x32_bf16(                  \
            afr[mt], bfr[nt], acc[mt][nt], 0, 0, 0);                            \
  }

  STEP(b0, b2, 0, 1) STEP(b1, b0, 1, 1) STEP(b2, b1, 2, 1) STEP(b0, b2, 3, 1)
  STEP(b1, b0, 4, 1) STEP(b2, b1, 5, 1) STEP(b0, b2, 6, 0) STEP(b1, b0, 7, 0)
#undef STEP
#undef LOADB

  float njc[2];
#pragma unroll
  for (int nt = 0; nt < 2; ++nt) {
    float v = njp[nt];
    v += __shfl_xor(v, 16);
    v += __shfl_xor(v, 32);
    njc[nt] = v;
  }

  __syncthreads();   // all waves done reading A; smem becomes the d-tile

#pragma unroll
  for (int mt = 0; mt < 4; ++mt) {
#pragma unroll
    for (int r = 0; r < 4; ++r) {
      const int pair = mt * 16 + kq * 4 + r;
      const float np = n_p[pair];
#pragma unroll
      for (int nt = 0; nt < 2; ++nt) {
        const int col = w * 32 + nt * 16 + m_l;
        float d = np + njc[nt] - 2.0f * acc[mt][nt][r];
        smem[pair * 256 + (col ^ (pair & 31))] = fmaxf(d, 0.0f);
      }
    }
  }
  __syncthreads();

  const int pp = tid & 63, q = tid >> 6;
  float t5[5] = {SENT, SENT, SENT, SENT, SENT};
#pragma unroll 4
  for (int i = 0; i < 32; ++i) {
    const int col = q * 32 + i;
    float v = smem[pp * 256 + (col ^ (pp & 31))];
    top5_insert(t5, v);
  }
  __syncthreads();
#pragma unroll
  for (int k = 0; k < 5; ++k) smem[tid * 5 + k] = t5[k];
  __syncthreads();
  if (tid < 64) {
    float m5[5] = {SENT, SENT, SENT, SENT, SENT};
    for (int g = 0; g < 8; ++g)
#pragma unroll
      for (int k = 0; k < 5; ++k) top5_insert(m5, smem[(g * 64 + tid) * 5 + k]);
    float* cc = cand + (size_t)blockIdx.x * (NP_ * 5) + tid * 5;
#pragma unroll
    for (int k = 0; k < 5; ++k) cc[k] = m5[k];
  }
}

// K3: reduce 1024 blocks' candidates -> per-pair mean of 5 smallest, then
// fused deterministic final sum: fixed-point (2^20) device-scope atomic adds
// (integer addition is order-invariant -> bitwise deterministic); the last of
// the 64 blocks converts and writes the output.
__global__ void topk_reduce_kernel(const float* __restrict__ cand,
                                   unsigned long long* __restrict__ acc,
                                   unsigned* __restrict__ cnt,
                                   float* __restrict__ out) {
  __shared__ float lds[256 * 5];
  const int p = blockIdx.x, tid = threadIdx.x;
  float t5[5] = {SENT, SENT, SENT, SENT, SENT};
  for (int b = tid; b < NBLK_; b += 256) {
    const float* cc = cand + (size_t)b * (NP_ * 5) + p * 5;
#pragma unroll
    for (int k = 0; k < 5; ++k) top5_insert(t5, cc[k]);
  }
#pragma unroll
  for (int k = 0; k < 5; ++k) lds[tid * 5 + k] = t5[k];
  __syncthreads();
  float m2[5] = {SENT, SENT, SENT, SENT, SENT};
  if (tid < 32) {
    for (int t2 = tid * 8; t2 < tid * 8 + 8; ++t2)
#pragma unroll
      for (int k = 0; k < 5; ++k) top5_insert(m2, lds[t2 * 5 + k]);
  }
  __syncthreads();
  if (tid < 32) {
#pragma unroll
    for (int k = 0; k < 5; ++k) lds[tid * 5 + k] = m2[k];
  }
  __syncthreads();
  if (tid == 0) {
    float f[5] = {SENT, SENT, SENT, SENT, SENT};
    for (int t2 = 0; t2 < 32; ++t2)
#pragma unroll
      for (int k = 0; k < 5; ++k) top5_insert(f, lds[t2 * 5 + k]);
    const float mean5 = (f[0] + f[1] + f[2] + f[3] + f[4]) * 0.2f;
    const unsigned long long fx =
        (unsigned long long)(long long)(mean5 * FIXSCALE);  // d >= 0
    atomicAdd(acc, fx);           // device-scope, order-invariant
    __threadfence();
    const unsigned prev = atomicAdd(cnt, 1u);
    if (prev == NP_ - 1) {
      const unsigned long long total = atomicAdd(acc, 0ull);  // coherent read
      out[0] = (float)((double)total / (FIXSCALE * (double)NP_));
    }
  }
}

extern "C" void kernel_launch(void* const* d_in, const int* in_sizes, int n_in,
                              void* d_out, int out_size, void* d_ws, size_t ws_size,
                              hipStream_t stream) {
  const float* f1 = (const float*)d_in[0];
  const float* f2 = (const float*)d_in[1];
  const void* pairs = d_in[2];
  float* out = (float*)d_out;
  float* ws = (float*)d_ws;

  float*              n_p  = ws;                         // 64 f
  unsigned short*     selb = (unsigned short*)(ws + 64); // 16384 ushort (32KB)
  float*              cand = ws + 64 + 8192;             // 1024*64*5 = 327680 f
  unsigned long long* acc  = (unsigned long long*)(ws + 64 + 8192 + 327680);
  unsigned*           cnt  = (unsigned*)(ws + 64 + 8192 + 327680 + 2);

  gather_sel_kernel<<<NP_, 256, 0, stream>>>(f1, pairs, selb, n_p, acc, cnt);
  dist_topk_kernel<<<NBLK_, 512, 0, stream>>>(f2, selb, n_p, cand);
  topk_reduce_kernel<<<NP_, 256, 0, stream>>>(cand, acc, cnt, out);
}